// Round 10
// baseline (614.114 us; speedup 1.0000x reference)
//
#include <hip/hip_runtime.h>
#include <hip/hip_bf16.h>
#include <math.h>

// Problem constants
#define NW    32768   // B*W = 512*64 windows
#define G     8       // windows per block
#define NBLK  (NW / G)
#define NT    512     // 8 waves/block: occupancy via waves-per-block, not blocks

// Dims
#define ND    172     // NODE_DIM = EDGE_DIM = TIME_DIM
#define EVD   347     // EVENT_DIM
#define HID   64
#define D2    128
#define MLPD  76

// ---- Workspace layout ----
// [0, 222208) bytes : bf16 MFMA B-fragments
//   fragment = 64 lanes x 8 bf16; addr = (frag_id*64 + lane)*8; lane=(q<<4)|mr;
//   element j of lane: B[n = nt*16+mr][k = ks*32+q*8+j] (0 if OOB).
#define W1OFF  0
#define G1OFF  (121 * 512)
#define G2OFF  (145 * 512)
#define ATTOFF (153 * 512)
#define NFRAG  217          // bf16 region = 217*512 bf16 = 222208 B
// [222208, 317440) bytes : fp32 k-tiled transposed tables for phase-3 layers.
//   table[kb][n] = float4(w[n][4kb..4kb+3]); coalesced: lane n reads [kb][n].
#define WSF_BYTE_OFF 222208
#define M1OFF4 0            // att_m1 [32][64]  (K=128)
#define M2OFF4 2048         // att_m2 [16][64]  (K=64)
#define W1OFF4 3072         // mlp_w1 [20][80]  (K=76 pad 80, n pad 80, zeros)
#define W2OFF4 4672         // mlp_w2 [20][64]  (K=76 pad 80, zeros)
#define NF4    5952         // total float4 = 95232 B; ws total = 317440 B

// ---- LDS byte layout (26112 B), liveness identical to R8/R9 ----
//  ph0 : write EF[24][360] @ [0,17280)
//  ph1 : MFMA reads EF rows 0..23 only (a1 clamped).  __syncthreads().
//        Epilogue writes EV[24] rows = U rows 24..47 @ [9600,19200).
//  2a  : EV reads hoisted to regs; writes U rows 0..23 @ [0,9600) and
//        24..47 @ [9600,19200) (over EV; reads done; rows wv-disjoint).
//  2b  : reads U[48][200] @ [0,19200) (all 48 rows valid, M=3 m-tiles);
//        writes H[48][72] @ [19200,26112).
//  2c  : reads H; writes FEATB[24][136] @ [0,6528), SRCF f32[8][128] @ [6528,10624)
//  2d  : reads FEATB (a1 row clamped <=23); writes PQ f32[24][128] @ [10624,22912)
//        (overlaps dead H - OK)
//  ph3 : reads PQ,SRCF; scratch SC f32[8][204] @ [0,6528) (FEATB dead).
//        SC tail read-overrun (<=16B) hits finite floats x ZERO k-pad weights.
#define B_EF    0
#define B_U     0
#define B_EV    9600      // == byte of U row 24 (EVS==US==200)
#define B_H     19200
#define B_FEATB 0
#define B_SRCF  6528
#define B_PQ    10624
#define B_SC    0
#define LDS_BYTES 26112

#define EFS 360
#define EVS 200
#define US  200
#define HS  72
#define FBS 136
#define SCS 204

typedef __attribute__((ext_vector_type(8))) short bf16x8;
typedef __attribute__((ext_vector_type(4))) float f32x4;

// inline function, NOT a macro — macro params collide with .x/.w member tokens
static __device__ __forceinline__ float dot4(float acc, const float4 a, const float4 b) {
  acc = fmaf(a.x, b.x, acc);
  acc = fmaf(a.y, b.y, acc);
  acc = fmaf(a.z, b.z, acc);
  acc = fmaf(a.w, b.w, acc);
  return acc;
}

static __device__ __forceinline__ short f2bf(float f) {
  union { __hip_bfloat16 h; short s; } u;
  u.h = __float2bfloat16(f);
  return u.s;
}
static __device__ __forceinline__ float bf2f(short s) {
  union { float f; unsigned u; } u;
  u.u = ((unsigned)(unsigned short)s) << 16;
  return u.f;
}

// ============ prep: pack all MFMA weights as bf16 fragments into ws ============
__global__ __launch_bounds__(256) void prep_weights(
    const float* __restrict__ w1, const float* __restrict__ g1,
    const float* __restrict__ g2, const float* __restrict__ a1,
    const float* __restrict__ a2, short* __restrict__ ws)
{
  const int t = blockIdx.x * 256 + threadIdx.x;
  if (t >= NFRAG * 64) return;
  const int fid  = t >> 6;
  const int lane = t & 63;
  const int q = lane >> 4, mr = lane & 15;
  bf16x8 o;
  if (fid < 121) {
    const int nt = fid / 11, ks = fid - 11 * nt;
    const int n = nt * 16 + mr, k0 = ks * 32 + q * 8;
#pragma unroll
    for (int j = 0; j < 8; ++j) {
      const int k = k0 + j;
      o[j] = (n < ND && k < EVD) ? f2bf(w1[n * EVD + k]) : (short)0;
    }
  } else if (fid < 145) {
    const int f = fid - 121, nt = f / 6, ks = f - 6 * nt;
    const int n = nt * 16 + mr, k0 = ks * 32 + q * 8;
#pragma unroll
    for (int j = 0; j < 8; ++j) {
      const int k = k0 + j;
      o[j] = (k < ND) ? f2bf(g1[n * ND + k]) : (short)0;
    }
  } else if (fid < 153) {
    const int f = fid - 145, nt = f / 2, ks = f - 2 * nt;
    const int n = nt * 16 + mr, k0 = ks * 32 + q * 8;
#pragma unroll
    for (int j = 0; j < 8; ++j) o[j] = f2bf(g2[n * HID + k0 + j]);
  } else {
    const int f = fid - 153, nt = f / 4, ks = f - 4 * nt;
    const int n = nt * 16 + mr, k0 = ks * 32 + q * 8;
    const float* src = (n < D2) ? (a1 + n * D2) : (a2 + (n - D2) * D2);
#pragma unroll
    for (int j = 0; j < 8; ++j) o[j] = f2bf(src[k0 + j]);
  }
  *(bf16x8*)&ws[(long)t * 8] = o;
}

// ============ prep: fp32 k-tiled transposed tables for phase-3 layers ============
__global__ __launch_bounds__(256) void prep_wf(
    const float* __restrict__ m1, const float* __restrict__ m2,
    const float* __restrict__ w1, const float* __restrict__ w2,
    float4* __restrict__ wf)
{
  const int t = blockIdx.x * 256 + threadIdx.x;
  if (t >= NF4) return;
  float4 o; o.x = 0.f; o.y = 0.f; o.z = 0.f; o.w = 0.f;
  if (t < M2OFF4) {                        // att_m1: [kb<32][n<64], K=128
    const int kb = t >> 6, n = t & 63;
    const float* s = m1 + n * D2 + kb * 4;
    o.x = s[0]; o.y = s[1]; o.z = s[2]; o.w = s[3];
  } else if (t < W1OFF4) {                 // att_m2: [kb<16][n<64], K=64
    const int u = t - M2OFF4, kb = u >> 6, n = u & 63;
    const float* s = m2 + n * HID + kb * 4;
    o.x = s[0]; o.y = s[1]; o.z = s[2]; o.w = s[3];
  } else if (t < W2OFF4) {                 // mlp_w1: [kb<20][n<80], pads zeroed
    const int u = t - W1OFF4, kb = u / 80, n = u - kb * 80;
    if (n < MLPD) {
#pragma unroll
      for (int j = 0; j < 4; ++j) {
        const int k = kb * 4 + j;
        ((float*)&o)[j] = (k < MLPD) ? w1[n * MLPD + k] : 0.f;
      }
    }
  } else {                                 // mlp_w2: [kb<20][n<64], k-pad zeroed
    const int u = t - W2OFF4, kb = u >> 6, n = u & 63;
#pragma unroll
    for (int j = 0; j < 4; ++j) {
      const int k = kb * 4 + j;
      ((float*)&o)[j] = (k < MLPD) ? w2[n * MLPD + k] : 0.f;
    }
  }
  wf[t] = o;
}

// __launch_bounds__(512, 4): min-waves/EU=4 caps VGPR at 128 — natural alloc
// (~56) fits with huge margin, so NO spill (R9's (512,8) forced VGPR=32 ->
// 136 MB scratch). At VGPR<=64 the HW still reaches 8 waves/SIMD.
__global__ __launch_bounds__(512, 4) void tempme_fused(
    const int*   __restrict__ node_idx,      // (NW, 6)
    const int*   __restrict__ edge_idx,      // (NW, 3)
    const int*   __restrict__ cat_feat,      // (NW, 1)
    const float* __restrict__ t_records,     // (NW, 3)
    const float* __restrict__ edge_identify, // (NW, 3, 3)
    const float* __restrict__ node_embed,    // (10000, 172)
    const float* __restrict__ edge_embed,    // (200000, 172)
    const float* __restrict__ basis_freq,    // (172,)
    const float* __restrict__ phase,         // (172,)
    const float* __restrict__ lin_event_b,   // (172,)
    const float* __restrict__ gcn_b1,        // (64,)
    const float* __restrict__ gcn_b2,        // (64,)
    const float* __restrict__ att_w1_b,      // (128,)
    const float* __restrict__ att_w2_b,      // (128,)
    const float* __restrict__ att_m1_b,      // (64,)
    const float* __restrict__ att_m2_b,      // (64,)
    const float* __restrict__ mlp_b1,        // (76,)
    const float* __restrict__ mlp_b2,        // (64,)
    const float* __restrict__ mlp_w3,        // (1, 64)
    const float* __restrict__ mlp_b3,        // (1,)
    const short* __restrict__ ws,            // packed bf16 weights
    const float4* __restrict__ wsf,          // packed fp32 phase-3 tables
    float*       __restrict__ out)           // (NW,)
{
  __shared__ __align__(16) unsigned char smem[LDS_BYTES];
  short* EF    = (short*)&smem[B_EF];
  short* EV    = (short*)&smem[B_EV];
  short* U     = (short*)&smem[B_U];
  short* Hs    = (short*)&smem[B_H];
  short* FEATB = (short*)&smem[B_FEATB];
  float* SRCF  = (float*)&smem[B_SRCF];
  float* PQ    = (float*)&smem[B_PQ];
  float* SC    = (float*)&smem[B_SC];

  const int tid  = threadIdx.x;
  const int lane = tid & 63;
  const int wv   = tid >> 6;    // 0..7
  const int q    = lane >> 4;   // MFMA quad
  const int mr   = lane & 15;   // MFMA row/col-within-tile
  const int bw0  = blockIdx.x * G;

  // ============ prefetch A: indices (wave-uniform scalar loads) ============
  int   eidx_[3], si_[3], ti_[3], rid_[3];
  float dt_[3];
#pragma unroll
  for (int i = 0; i < 3; ++i) {
    const int r = wv + 8 * i;          // 0..23
    const int g = r / 3;
    const int l = r - 3 * g;
    const int bw = bw0 + g;
    const int rid = bw * 3 + l;
    rid_[i]  = rid;
    eidx_[i] = edge_idx[rid];
    si_[i]   = node_idx[bw * 6 + 2 * l];
    ti_[i]   = node_idx[bw * 6 + 2 * l + 1];
    dt_[i]   = t_records[bw * 3 + 2] - t_records[rid];
  }

  // ============ prefetch B: edge-row gathers (9 loads all in flight) ============
  float pg[3][3];
#pragma unroll
  for (int i = 0; i < 3; ++i) {
    const float* erow = edge_embed + (long)eidx_[i] * ND;
#pragma unroll
    for (int c = 0; c < 3; ++c) {
      const int k = c * 64 + lane;
      float v = 0.f;
      if (k < ND)            v = erow[k];
      else if (k < ND + 3)   v = edge_identify[rid_[i] * 3 + (k - ND)];
      pg[i][c] = v;
    }
  }

  // ============ phase 0: build ef bf16[24][360] from prefetched regs + cos ============
#pragma unroll
  for (int i = 0; i < 3; ++i) {
    const int r = wv + 8 * i;
    const float dt = dt_[i];
#pragma unroll
    for (int c = 0; c < 6; ++c) {
      const int k = c * 64 + lane;   // 0..383
      float v;
      if (c < 3) {
        v = pg[i][c];
        if (k >= ND + 3) {           // c==2 lanes 47..63 -> time features
          const int d = k - (ND + 3);
          v = __cosf(fmaf(dt, basis_freq[d], phase[d]));
        }
      } else {
        v = 0.f;
        if (k < EVD) {
          const int d = k - (ND + 3);
          v = __cosf(fmaf(dt, basis_freq[d], phase[d]));
        }
      }
      if (k < 352) EF[r * EFS + k] = f2bf(v);   // 347..351 = K-pad (zero)
    }
  }

  // ============ prefetch C: node-row gathers (18 loads) — latency hides under
  // the barrier + phase-1 MFMA ============
  float ps[3][3], pt[3][3];
#pragma unroll
  for (int i = 0; i < 3; ++i) {
    const float* srow = node_embed + (long)si_[i] * ND;
    const float* trow = node_embed + (long)ti_[i] * ND;
#pragma unroll
    for (int c = 0; c < 3; ++c) {
      const int k = c * 64 + lane;
      float sv = 0.f, tv = 0.f;
      if (k < ND) { sv = srow[k]; tv = trow[k]; }
      ps[i][c] = sv;
      pt[i][c] = tv;
    }
  }
  __syncthreads();

  // ============ phase 1 (MFMA): EV[24][172] = EF[24][347] @ lin_event_w^T ============
  // 11 n-tiles over 8 waves: wave w owns nt=w, and nt=w+8 for w<3.
  // a1 row clamped <=23 (no unwritten-LDS reads; C rows 24-31 masked).
  {
    const int a1r = (mr < 8) ? (16 + mr) : 23;
    const int nnt = (wv < 3) ? 2 : 1;
    f32x4 acc[2][2];
#pragma unroll
    for (int t = 0; t < 2; ++t)
#pragma unroll
      for (int mt = 0; mt < 2; ++mt) acc[t][mt] = (f32x4){0.f, 0.f, 0.f, 0.f};

#pragma unroll 2
    for (int ks = 0; ks < 11; ++ks) {
      const int k0 = ks * 32 + q * 8;
      const bf16x8 a0 = *(const bf16x8*)&EF[mr * EFS + k0];
      const bf16x8 a1 = *(const bf16x8*)&EF[a1r * EFS + k0];
#pragma unroll 1
      for (int t = 0; t < nnt; ++t) {
        const int nt = wv + 8 * t;
        const bf16x8 b = *(const bf16x8*)&ws[W1OFF + ((nt * 11 + ks) * 64 + lane) * 8];
        acc[t][0] = __builtin_amdgcn_mfma_f32_16x16x32_bf16(a0, b, acc[t][0], 0, 0, 0);
        acc[t][1] = __builtin_amdgcn_mfma_f32_16x16x32_bf16(a1, b, acc[t][1], 0, 0, 0);
      }
    }
    __syncthreads();   // all waves done reading EF before EV overwrites it
#pragma unroll 1
    for (int t = 0; t < nnt; ++t) {
      const int n = (wv + 8 * t) * 16 + mr;
      const float bo = (n < ND) ? lin_event_b[n] : 0.f;
#pragma unroll
      for (int mt = 0; mt < 2; ++mt)
#pragma unroll
        for (int reg = 0; reg < 4; ++reg) {
          const int m = mt * 16 + q * 4 + reg;
          if (m < 24) EV[m * EVS + n] = f2bf(acc[t][mt][reg] + bo);
        }
    }
  }
  __syncthreads();

  // ============ phase 2a: U rows from prefetched node regs + EV ============
  // EV reads hoisted to registers FIRST; then u0 -> rows 0..23 (dead EF),
  // u1 -> rows 24..47 (over EV; reads done; row ownership wv-disjoint).
  {
    float ev[3][3];
#pragma unroll
    for (int i = 0; i < 3; ++i) {
      const int r = wv + 8 * i;
#pragma unroll
      for (int c = 0; c < 3; ++c) {
        const int k = c * 64 + lane;
        ev[i][c] = (k < ND) ? bf2f(EV[r * EVS + k]) : 0.f;
      }
    }
#pragma unroll
    for (int i = 0; i < 3; ++i) {
      const int r = wv + 8 * i;
#pragma unroll
      for (int c = 0; c < 3; ++c) {
        const int k = c * 64 + lane;  // 0..191
        float u0v = 0.f, u1v = 0.f;
        if (k < ND) {
          const float e = ev[i][c];
          const float s = ps[i][c];
          const float t = pt[i][c];
          u0v = s + fmaxf(t + e, 0.f);
          u1v = t + fmaxf(s + e, 0.f);
        }
        U[r * US + k]        = f2bf(u0v);   // k in [172,192) zero = K-pad
        U[(24 + r) * US + k] = f2bf(u1v);   // overwrites EV row r
      }
    }
  }
  __syncthreads();

  // ============ phase 2b (MFMA): H[48][64] = relu(U[48][192] @ gcn_w1^T + b1) ============
  // M=48 = 3 m-tiles exactly (no garbage rows). 12 (mtile,ntile) pairs over
  // 8 waves: wave w does p=w and p=w+8 (w<4).
  {
    const int np = (wv < 4) ? 2 : 1;
#pragma unroll 1
    for (int pp = 0; pp < np; ++pp) {
      const int p = wv + 8 * pp;       // 0..11
      const int mtile = p >> 2, ntb = p & 3;
      const int urow = mtile * 16 + mr;
      f32x4 acc = (f32x4){0.f, 0.f, 0.f, 0.f};
#pragma unroll 2
      for (int ks = 0; ks < 6; ++ks) {
        const int k0 = ks * 32 + q * 8;
        const bf16x8 a = *(const bf16x8*)&U[urow * US + k0];
        const bf16x8 b = *(const bf16x8*)&ws[G1OFF + ((ntb * 6 + ks) * 64 + lane) * 8];
        acc = __builtin_amdgcn_mfma_f32_16x16x32_bf16(a, b, acc, 0, 0, 0);
      }
      const int j = ntb * 16 + mr;
      const float b1 = gcn_b1[j];
#pragma unroll
      for (int reg = 0; reg < 4; ++reg) {
        const int m = mtile * 16 + q * 4 + reg;   // 0..47
        Hs[m * HS + j] = f2bf(fmaxf(acc[reg] + b1, 0.f));
      }
    }
  }
  __syncthreads();

  // ============ phase 2c (MFMA): FEATB/SRCF = H @ gcn_w2^T + b2 ============
  {
    const int np = (wv < 4) ? 2 : 1;
#pragma unroll 1
    for (int pp = 0; pp < np; ++pp) {
      const int p = wv + 8 * pp;       // 0..11
      const int mtile = p >> 2, ntb = p & 3;
      const int hrow = mtile * 16 + mr;
      f32x4 acc = (f32x4){0.f, 0.f, 0.f, 0.f};
#pragma unroll
      for (int ks = 0; ks < 2; ++ks) {
        const int k0 = ks * 32 + q * 8;
        const bf16x8 a = *(const bf16x8*)&Hs[hrow * HS + k0];
        const bf16x8 b = *(const bf16x8*)&ws[G2OFF + ((ntb * 2 + ks) * 64 + lane) * 8];
        acc = __builtin_amdgcn_mfma_f32_16x16x32_bf16(a, b, acc, 0, 0, 0);
      }
      const int j = ntb * 16 + mr;
      const float b2 = gcn_b2[j];
#pragma unroll
      for (int reg = 0; reg < 4; ++reg) {
        const int m = mtile * 16 + q * 4 + reg;   // 0..47
        const int d = (m < 24) ? 0 : 1;
        const int r = m - 24 * d;
        const float v = acc[reg] + b2;
        const int n = d * HID + j;
        FEATB[r * FBS + n] = f2bf(v);
        if (r % 3 == 2) SRCF[(r / 3) * 128 + n] = v;   // src feat, fp32
      }
    }
  }
  __syncthreads();

  // ============ phase 2d (MFMA): PQ = feat @ [att_w1 | att_w2]^T + bias ============
  // 16 n-tiles over 8 waves: nt = wv*2 + tt.
  {
    const int fr1 = (16 + mr < 24) ? (16 + mr) : 23;   // a1 garbage-row clamp
    f32x4 acc[2][2];
#pragma unroll
    for (int tt = 0; tt < 2; ++tt)
#pragma unroll
      for (int mt = 0; mt < 2; ++mt) acc[tt][mt] = (f32x4){0.f, 0.f, 0.f, 0.f};
#pragma unroll 2
    for (int ks = 0; ks < 4; ++ks) {
      const int k0 = ks * 32 + q * 8;
      const bf16x8 a0 = *(const bf16x8*)&FEATB[mr * FBS + k0];
      const bf16x8 a1 = *(const bf16x8*)&FEATB[fr1 * FBS + k0];
#pragma unroll 1
      for (int tt = 0; tt < 2; ++tt) {
        const int nt = wv * 2 + tt;
        const bf16x8 b = *(const bf16x8*)&ws[ATTOFF + ((nt * 4 + ks) * 64 + lane) * 8];
        acc[tt][0] = __builtin_amdgcn_mfma_f32_16x16x32_bf16(a0, b, acc[tt][0], 0, 0, 0);
        acc[tt][1] = __builtin_amdgcn_mfma_f32_16x16x32_bf16(a1, b, acc[tt][1], 0, 0, 0);
      }
    }
#pragma unroll 1
    for (int tt = 0; tt < 2; ++tt) {
      const int n = (wv * 2 + tt) * 16 + mr;   // 0..255
      const float bias = (n < D2) ? att_w1_b[n] : att_w2_b[n - D2];
#pragma unroll
      for (int mt = 0; mt < 2; ++mt)
#pragma unroll
        for (int reg = 0; reg < 4; ++reg) {
          const int m = mt * 16 + q * 4 + reg;
          if (m < 24) {
            const int l = m % 3;
            if (l == 2) { if (n < D2)  PQ[m * 128 + n]        = acc[tt][mt][reg] + bias; }
            else        { if (n >= D2) PQ[m * 128 + (n - D2)] = acc[tt][mt][reg] + bias; }
          }
        }
    }
  }
  __syncthreads();

  // ============ phase 3: softmax/out + MLP head — ONE window per wave ============
  {
    const int g = wv;
    float* Aw = SC + g * SCS;       // 128-float activation slot
    float* Bw = Aw + 128;           // 76-float hidden slot

    // softmax + out
    {
      const float p0  = PQ[(3 * g + 2) * 128 + lane];
      const float p1  = PQ[(3 * g + 2) * 128 + 64 + lane];
      const float q00 = PQ[(3 * g + 0) * 128 + lane];
      const float q01 = PQ[(3 * g + 0) * 128 + 64 + lane];
      const float q10 = PQ[(3 * g + 1) * 128 + lane];
      const float q11 = PQ[(3 * g + 1) * 128 + 64 + lane];
      float s0 = p0 * q00 + p1 * q01;
      float s1 = p0 * q10 + p1 * q11;
#pragma unroll
      for (int off = 32; off >= 1; off >>= 1) {
        s0 += __shfl_xor(s0, off, 64);
        s1 += __shfl_xor(s1, off, 64);
      }
      const float mx = fmaxf(s0, s1);
      const float e0 = __expf(s0 - mx), e1 = __expf(s1 - mx);
      const float inv = 1.f / (e0 + e1);
      const float a0 = e0 * inv, a1 = e1 * inv;
      Aw[lane]      = SRCF[g * 128 + lane]      + a0 * q00 + a1 * q10;
      Aw[64 + lane] = SRCF[g * 128 + 64 + lane] + a0 * q01 + a1 * q11;
    }

    const float4* M1P = wsf + M1OFF4;
    const float4* M2P = wsf + M2OFF4;
    const float4* W1P = wsf + W1OFF4;
    const float4* W2P = wsf + W2OFF4;

    // m1 = relu(att_m1 @ out + b): K=128 (dual accumulator chains)
    {
      float aa0 = 0.f, aa1 = 0.f;
#pragma unroll 4
      for (int kb = 0; kb < 32; kb += 2) {
        const float4 w0 = M1P[kb * 64 + lane];
        const float4 w1 = M1P[(kb + 1) * 64 + lane];
        const float4 x0 = *(const float4*)&Aw[kb * 4];
        const float4 x1 = *(const float4*)&Aw[kb * 4 + 4];
        aa0 = dot4(aa0, w0, x0); aa1 = dot4(aa1, w1, x1);
      }
      Bw[lane] = fmaxf(att_m1_b[lane] + aa0 + aa1, 0.f);
    }

    // h = att_m2 @ m1 + b: K=64
    float hv;
    {
      float aa0 = 0.f, aa1 = 0.f;
#pragma unroll 4
      for (int kb = 0; kb < 16; kb += 2) {
        const float4 w0 = M2P[kb * 64 + lane];
        const float4 w1 = M2P[(kb + 1) * 64 + lane];
        const float4 x0 = *(const float4*)&Bw[kb * 4];
        const float4 x1 = *(const float4*)&Bw[kb * 4 + 4];
        aa0 = dot4(aa0, w0, x0); aa1 = dot4(aa1, w1, x1);
      }
      hv = att_m2_b[lane] + aa0 + aa1;
    }

    // x = concat(h, one_hot(cat,12), 0-pad to 80) -> Aw (out is dead)
    Aw[lane] = hv;
    if (lane < 16) {
      const int ca = cat_feat[bw0 + g];
      Aw[64 + lane] = (lane < 12 && ca == lane) ? 1.f : 0.f;
    }

    // h1 = relu(mlp_w1 @ x + b1): 76 outs (n=lane, n2=64+lane for lane<12), K=80
    // Reads of Bw[76..79] later hit finite floats x ZERO k-pad weights -> 0.
    {
      float an = 0.f, an2 = 0.f;
      const int l2 = 64 + (lane & 15);
#pragma unroll 4
      for (int kb = 0; kb < 20; ++kb) {
        const float4 wn  = W1P[kb * 80 + lane];
        const float4 wn2 = W1P[kb * 80 + l2];
        const float4 x  = *(const float4*)&Aw[kb * 4];
        an  = dot4(an,  wn,  x);
        an2 = dot4(an2, wn2, x);
      }
      Bw[lane] = fmaxf(mlp_b1[lane] + an, 0.f);
      if (lane < 12) Bw[64 + lane] = fmaxf(mlp_b1[64 + lane] + an2, 0.f);
    }

    // h2 = relu(mlp_w2 @ h1 + b2); z = mlp_w3 @ h2 + b3; sigmoid
    {
      float ha = 0.f;
#pragma unroll 4
      for (int kb = 0; kb < 20; ++kb) {
        const float4 w = W2P[kb * 64 + lane];
        const float4 x = *(const float4*)&Bw[kb * 4];
        ha = dot4(ha, w, x);
      }
      const float h2 = fmaxf(mlp_b2[lane] + ha, 0.f);
      float zz = mlp_w3[lane] * h2;
#pragma unroll
      for (int off = 32; off >= 1; off >>= 1) zz += __shfl_xor(zz, off, 64);
      if (lane == 0) out[bw0 + g] = 1.f / (1.f + __expf(-(zz + mlp_b3[0])));
    }
  }
}

extern "C" void kernel_launch(void* const* d_in, const int* in_sizes, int n_in,
                              void* d_out, int out_size, void* d_ws, size_t ws_size,
                              hipStream_t stream) {
  short* ws = (short*)d_ws;
  float4* wsf = (float4*)((char*)d_ws + WSF_BYTE_OFF);
  prep_weights<<<(NFRAG * 64 + 255) / 256, 256, 0, stream>>>(
      (const float*)d_in[10],  // lin_event_w
      (const float*)d_in[12],  // gcn_w1
      (const float*)d_in[14],  // gcn_w2
      (const float*)d_in[16],  // att_w1_w
      (const float*)d_in[18],  // att_w2_w
      ws);
  prep_wf<<<(NF4 + 255) / 256, 256, 0, stream>>>(
      (const float*)d_in[20],  // att_m1_w
      (const float*)d_in[22],  // att_m2_w
      (const float*)d_in[24],  // mlp_w1
      (const float*)d_in[26],  // mlp_w2
      wsf);
  tempme_fused<<<NBLK, NT, 0, stream>>>(
      (const int*)d_in[0],    // node_idx
      (const int*)d_in[1],    // edge_idx
      (const int*)d_in[2],    // cat_feat
      (const float*)d_in[3],  // t_records
      (const float*)d_in[4],  // edge_identify
      // d_in[5] cut_time_l unused by reference
      (const float*)d_in[6],  // node_embed
      (const float*)d_in[7],  // edge_embed
      (const float*)d_in[8],  // basis_freq
      (const float*)d_in[9],  // phase
      (const float*)d_in[11],  // lin_event_b
      (const float*)d_in[13],  // gcn_b1
      (const float*)d_in[15],  // gcn_b2
      (const float*)d_in[17],  // att_w1_b
      (const float*)d_in[19],  // att_w2_b
      (const float*)d_in[21],  // att_m1_b
      (const float*)d_in[23],  // att_m2_b
      (const float*)d_in[25],  // mlp_b1
      (const float*)d_in[27],  // mlp_b2
      (const float*)d_in[28],  // mlp_w3
      (const float*)d_in[29],  // mlp_b3
      ws, wsf,
      (float*)d_out);
}

// Round 11
// 448.961 us; speedup vs baseline: 1.3679x; 1.3679x over previous
//
#include <hip/hip_runtime.h>
#include <hip/hip_bf16.h>
#include <math.h>

// Problem constants
#define NW    32768   // B*W = 512*64 windows
#define G     8       // windows per block
#define NBLK  (NW / G)
#define NT    512     // 8 waves/block: occupancy via waves-per-block

// Dims
#define ND    172     // NODE_DIM = EDGE_DIM = TIME_DIM
#define EVD   347     // EVENT_DIM
#define HID   64
#define D2    128
#define MLPD  76

// ---- Workspace layout ----
// [0, 222208) bytes : bf16 MFMA B-fragments
//   fragment = 64 lanes x 8 bf16; addr = (frag_id*64 + lane)*8; lane=(q<<4)|mr;
//   element j of lane: B[n = nt*16+mr][k = ks*32+q*8+j] (0 if OOB).
#define W1OFF  0
#define G1OFF  (121 * 512)
#define G2OFF  (145 * 512)
#define ATTOFF (153 * 512)
#define NFRAG  217          // bf16 region = 217*512 bf16 = 222208 B
// [222208, 317440) bytes : fp32 k-tiled transposed tables for phase-3 layers.
//   table[kb][n] = float4(w[n][4kb..4kb+3]); coalesced: lane n reads [kb][n].
#define WSF_BYTE_OFF 222208
#define M1OFF4 0            // att_m1 [32][64]  (K=128)
#define M2OFF4 2048         // att_m2 [16][64]  (K=64)
#define W1OFF4 3072         // mlp_w1 [20][80]  (K=76 pad 80, n pad 80, zeros)
#define W2OFF4 4672         // mlp_w2 [20][64]  (K=76 pad 80, zeros)
#define NF4    5952         // total float4 = 95232 B; ws total = 317440 B

// ---- LDS byte layout (26112 B), liveness identical to R8/R9/R10 ----
//  ph0 : write EF[24][360] @ [0,17280)
//  ph1 : MFMA reads EF rows 0..23 only (a1 clamped).  __syncthreads().
//        Epilogue writes EV[24] rows = U rows 24..47 @ [9600,19200).
//  2a  : EV reads hoisted to regs; writes U rows 0..23 @ [0,9600) and
//        24..47 @ [9600,19200) (over EV; reads done; rows wv-disjoint).
//  2b  : reads U[48][200] @ [0,19200) (all 48 rows valid, M=3 m-tiles);
//        writes H[48][72] @ [19200,26112).
//  2c  : reads H; writes FEATB[24][136] @ [0,6528), SRCF f32[8][128] @ [6528,10624)
//  2d  : reads FEATB (a1 row clamped <=23); writes PQ f32[24][128] @ [10624,22912)
//        (overlaps dead H - OK)
//  ph3 : reads PQ,SRCF; scratch SC f32[8][204] @ [0,6528) (FEATB dead).
//        SC tail read-overrun (<=16B) hits finite floats x ZERO k-pad weights.
#define B_EF    0
#define B_U     0
#define B_EV    9600      // == byte of U row 24 (EVS==US==200)
#define B_H     19200
#define B_FEATB 0
#define B_SRCF  6528
#define B_PQ    10624
#define B_SC    0
#define LDS_BYTES 26112

#define EFS 360
#define EVS 200
#define US  200
#define HS  72
#define FBS 136
#define SCS 204

typedef __attribute__((ext_vector_type(8))) short bf16x8;
typedef __attribute__((ext_vector_type(4))) float f32x4;

// inline function, NOT a macro — macro params collide with .x/.w member tokens
static __device__ __forceinline__ float dot4(float acc, const float4 a, const float4 b) {
  acc = fmaf(a.x, b.x, acc);
  acc = fmaf(a.y, b.y, acc);
  acc = fmaf(a.z, b.z, acc);
  acc = fmaf(a.w, b.w, acc);
  return acc;
}

static __device__ __forceinline__ short f2bf(float f) {
  union { __hip_bfloat16 h; short s; } u;
  u.h = __float2bfloat16(f);
  return u.s;
}
static __device__ __forceinline__ float bf2f(short s) {
  union { float f; unsigned u; } u;
  u.u = ((unsigned)(unsigned short)s) << 16;
  return u.f;
}

// ============ prep: pack all MFMA weights as bf16 fragments into ws ============
__global__ __launch_bounds__(256) void prep_weights(
    const float* __restrict__ w1, const float* __restrict__ g1,
    const float* __restrict__ g2, const float* __restrict__ a1,
    const float* __restrict__ a2, short* __restrict__ ws)
{
  const int t = blockIdx.x * 256 + threadIdx.x;
  if (t >= NFRAG * 64) return;
  const int fid  = t >> 6;
  const int lane = t & 63;
  const int q = lane >> 4, mr = lane & 15;
  bf16x8 o;
  if (fid < 121) {
    const int nt = fid / 11, ks = fid - 11 * nt;
    const int n = nt * 16 + mr, k0 = ks * 32 + q * 8;
#pragma unroll
    for (int j = 0; j < 8; ++j) {
      const int k = k0 + j;
      o[j] = (n < ND && k < EVD) ? f2bf(w1[n * EVD + k]) : (short)0;
    }
  } else if (fid < 145) {
    const int f = fid - 121, nt = f / 6, ks = f - 6 * nt;
    const int n = nt * 16 + mr, k0 = ks * 32 + q * 8;
#pragma unroll
    for (int j = 0; j < 8; ++j) {
      const int k = k0 + j;
      o[j] = (k < ND) ? f2bf(g1[n * ND + k]) : (short)0;
    }
  } else if (fid < 153) {
    const int f = fid - 145, nt = f / 2, ks = f - 2 * nt;
    const int n = nt * 16 + mr, k0 = ks * 32 + q * 8;
#pragma unroll
    for (int j = 0; j < 8; ++j) o[j] = f2bf(g2[n * HID + k0 + j]);
  } else {
    const int f = fid - 153, nt = f / 4, ks = f - 4 * nt;
    const int n = nt * 16 + mr, k0 = ks * 32 + q * 8;
    const float* src = (n < D2) ? (a1 + n * D2) : (a2 + (n - D2) * D2);
#pragma unroll
    for (int j = 0; j < 8; ++j) o[j] = f2bf(src[k0 + j]);
  }
  *(bf16x8*)&ws[(long)t * 8] = o;
}

// ============ prep: fp32 k-tiled transposed tables for phase-3 layers ============
__global__ __launch_bounds__(256) void prep_wf(
    const float* __restrict__ m1, const float* __restrict__ m2,
    const float* __restrict__ w1, const float* __restrict__ w2,
    float4* __restrict__ wf)
{
  const int t = blockIdx.x * 256 + threadIdx.x;
  if (t >= NF4) return;
  float4 o; o.x = 0.f; o.y = 0.f; o.z = 0.f; o.w = 0.f;
  if (t < M2OFF4) {                        // att_m1: [kb<32][n<64], K=128
    const int kb = t >> 6, n = t & 63;
    const float* s = m1 + n * D2 + kb * 4;
    o.x = s[0]; o.y = s[1]; o.z = s[2]; o.w = s[3];
  } else if (t < W1OFF4) {                 // att_m2: [kb<16][n<64], K=64
    const int u = t - M2OFF4, kb = u >> 6, n = u & 63;
    const float* s = m2 + n * HID + kb * 4;
    o.x = s[0]; o.y = s[1]; o.z = s[2]; o.w = s[3];
  } else if (t < W2OFF4) {                 // mlp_w1: [kb<20][n<80], pads zeroed
    const int u = t - W1OFF4, kb = u / 80, n = u - kb * 80;
    if (n < MLPD) {
#pragma unroll
      for (int j = 0; j < 4; ++j) {
        const int k = kb * 4 + j;
        ((float*)&o)[j] = (k < MLPD) ? w1[n * MLPD + k] : 0.f;
      }
    }
  } else {                                 // mlp_w2: [kb<20][n<64], k-pad zeroed
    const int u = t - W2OFF4, kb = u >> 6, n = u & 63;
#pragma unroll
    for (int j = 0; j < 4; ++j) {
      const int k = kb * 4 + j;
      ((float*)&o)[j] = (k < MLPD) ? w2[n * MLPD + k] : 0.f;
    }
  }
  wf[t] = o;
}

// Single-arg launch bounds: no min-wave constraint (R9's (512,8) forced
// VGPR=32; R10's (512,4) pinned occupancy to 4 waves/EU). Natural VGPR ~56-64.
// All accumulator arrays below are compile-time indexed (R9/R10's 139 MB
// scratch traffic came from runtime-indexed f32x4 acc[2][2] -> local memory).
__global__ __launch_bounds__(512) void tempme_fused(
    const int*   __restrict__ node_idx,      // (NW, 6)
    const int*   __restrict__ edge_idx,      // (NW, 3)
    const int*   __restrict__ cat_feat,      // (NW, 1)
    const float* __restrict__ t_records,     // (NW, 3)
    const float* __restrict__ edge_identify, // (NW, 3, 3)
    const float* __restrict__ node_embed,    // (10000, 172)
    const float* __restrict__ edge_embed,    // (200000, 172)
    const float* __restrict__ basis_freq,    // (172,)
    const float* __restrict__ phase,         // (172,)
    const float* __restrict__ lin_event_b,   // (172,)
    const float* __restrict__ gcn_b1,        // (64,)
    const float* __restrict__ gcn_b2,        // (64,)
    const float* __restrict__ att_w1_b,      // (128,)
    const float* __restrict__ att_w2_b,      // (128,)
    const float* __restrict__ att_m1_b,      // (64,)
    const float* __restrict__ att_m2_b,      // (64,)
    const float* __restrict__ mlp_b1,        // (76,)
    const float* __restrict__ mlp_b2,        // (64,)
    const float* __restrict__ mlp_w3,        // (1, 64)
    const float* __restrict__ mlp_b3,        // (1,)
    const short* __restrict__ ws,            // packed bf16 weights
    const float4* __restrict__ wsf,          // packed fp32 phase-3 tables
    float*       __restrict__ out)           // (NW,)
{
  __shared__ __align__(16) unsigned char smem[LDS_BYTES];
  short* EF    = (short*)&smem[B_EF];
  short* EV    = (short*)&smem[B_EV];
  short* U     = (short*)&smem[B_U];
  short* Hs    = (short*)&smem[B_H];
  short* FEATB = (short*)&smem[B_FEATB];
  float* SRCF  = (float*)&smem[B_SRCF];
  float* PQ    = (float*)&smem[B_PQ];
  float* SC    = (float*)&smem[B_SC];

  const int tid  = threadIdx.x;
  const int lane = tid & 63;
  const int wv   = tid >> 6;    // 0..7
  const int q    = lane >> 4;   // MFMA quad
  const int mr   = lane & 15;   // MFMA row/col-within-tile
  const int bw0  = blockIdx.x * G;

  // ============ prefetch A: indices (wave-uniform scalar loads) ============
  int   eidx_[3], si_[3], ti_[3], rid_[3];
  float dt_[3];
#pragma unroll
  for (int i = 0; i < 3; ++i) {
    const int r = wv + 8 * i;          // 0..23
    const int g = r / 3;
    const int l = r - 3 * g;
    const int bw = bw0 + g;
    const int rid = bw * 3 + l;
    rid_[i]  = rid;
    eidx_[i] = edge_idx[rid];
    si_[i]   = node_idx[bw * 6 + 2 * l];
    ti_[i]   = node_idx[bw * 6 + 2 * l + 1];
    dt_[i]   = t_records[bw * 3 + 2] - t_records[rid];
  }

  // ============ prefetch B: edge-row gathers (9 loads all in flight) ============
  float pg[3][3];
#pragma unroll
  for (int i = 0; i < 3; ++i) {
    const float* erow = edge_embed + (long)eidx_[i] * ND;
#pragma unroll
    for (int c = 0; c < 3; ++c) {
      const int k = c * 64 + lane;
      float v = 0.f;
      if (k < ND)            v = erow[k];
      else if (k < ND + 3)   v = edge_identify[rid_[i] * 3 + (k - ND)];
      pg[i][c] = v;
    }
  }

  // ============ phase 0: build ef bf16[24][360] from prefetched regs + cos ============
#pragma unroll
  for (int i = 0; i < 3; ++i) {
    const int r = wv + 8 * i;
    const float dt = dt_[i];
#pragma unroll
    for (int c = 0; c < 6; ++c) {
      const int k = c * 64 + lane;   // 0..383
      float v;
      if (c < 3) {
        v = pg[i][c];
        if (k >= ND + 3) {           // c==2 lanes 47..63 -> time features
          const int d = k - (ND + 3);
          v = __cosf(fmaf(dt, basis_freq[d], phase[d]));
        }
      } else {
        v = 0.f;
        if (k < EVD) {
          const int d = k - (ND + 3);
          v = __cosf(fmaf(dt, basis_freq[d], phase[d]));
        }
      }
      if (k < 352) EF[r * EFS + k] = f2bf(v);   // 347..351 = K-pad (zero)
    }
  }

  // ============ prefetch C: node-row gathers (18 loads) — latency hides under
  // the barrier + phase-1 MFMA ============
  float ps[3][3], pt[3][3];
#pragma unroll
  for (int i = 0; i < 3; ++i) {
    const float* srow = node_embed + (long)si_[i] * ND;
    const float* trow = node_embed + (long)ti_[i] * ND;
#pragma unroll
    for (int c = 0; c < 3; ++c) {
      const int k = c * 64 + lane;
      float sv = 0.f, tv = 0.f;
      if (k < ND) { sv = srow[k]; tv = trow[k]; }
      ps[i][c] = sv;
      pt[i][c] = tv;
    }
  }
  __syncthreads();

  // ============ phase 1 (MFMA): EV[24][172] = EF[24][347] @ lin_event_w^T ============
  // 11 n-tiles over 8 waves: wave w owns nt=w, plus nt=w+8 for w<3.
  // NAMED accumulators + wave-uniform guard: all register indices are
  // compile-time (no local-memory allocation — R9/R10's spill source).
  // a1 row clamped <=23 (no unwritten-LDS reads; C rows 24-31 masked).
  {
    const int a1r = (mr < 8) ? (16 + mr) : 23;
    const bool two = (wv < 3);
    f32x4 accA0 = (f32x4){0.f, 0.f, 0.f, 0.f};
    f32x4 accA1 = (f32x4){0.f, 0.f, 0.f, 0.f};
    f32x4 accB0 = (f32x4){0.f, 0.f, 0.f, 0.f};
    f32x4 accB1 = (f32x4){0.f, 0.f, 0.f, 0.f};

#pragma unroll 2
    for (int ks = 0; ks < 11; ++ks) {
      const int k0 = ks * 32 + q * 8;
      const bf16x8 a0 = *(const bf16x8*)&EF[mr * EFS + k0];
      const bf16x8 a1 = *(const bf16x8*)&EF[a1r * EFS + k0];
      {
        const bf16x8 b = *(const bf16x8*)&ws[W1OFF + ((wv * 11 + ks) * 64 + lane) * 8];
        accA0 = __builtin_amdgcn_mfma_f32_16x16x32_bf16(a0, b, accA0, 0, 0, 0);
        accA1 = __builtin_amdgcn_mfma_f32_16x16x32_bf16(a1, b, accA1, 0, 0, 0);
      }
      if (two) {
        const bf16x8 b = *(const bf16x8*)&ws[W1OFF + (((wv + 8) * 11 + ks) * 64 + lane) * 8];
        accB0 = __builtin_amdgcn_mfma_f32_16x16x32_bf16(a0, b, accB0, 0, 0, 0);
        accB1 = __builtin_amdgcn_mfma_f32_16x16x32_bf16(a1, b, accB1, 0, 0, 0);
      }
    }
    __syncthreads();   // all waves done reading EF before EV overwrites it
    {
      const int n = wv * 16 + mr;
      const float bo = (n < ND) ? lin_event_b[n] : 0.f;
#pragma unroll
      for (int reg = 0; reg < 4; ++reg) {
        const int m0 = q * 4 + reg;              // mt=0: rows 0-15, all <24
        EV[m0 * EVS + n] = f2bf(accA0[reg] + bo);
        const int m1 = 16 + q * 4 + reg;         // mt=1: rows 16-31
        if (m1 < 24) EV[m1 * EVS + n] = f2bf(accA1[reg] + bo);
      }
    }
    if (two) {
      const int n = (wv + 8) * 16 + mr;
      const float bo = (n < ND) ? lin_event_b[n] : 0.f;
#pragma unroll
      for (int reg = 0; reg < 4; ++reg) {
        const int m0 = q * 4 + reg;
        EV[m0 * EVS + n] = f2bf(accB0[reg] + bo);
        const int m1 = 16 + q * 4 + reg;
        if (m1 < 24) EV[m1 * EVS + n] = f2bf(accB1[reg] + bo);
      }
    }
  }
  __syncthreads();

  // ============ phase 2a: U rows from prefetched node regs + EV ============
  // EV reads hoisted to registers FIRST; then u0 -> rows 0..23 (dead EF),
  // u1 -> rows 24..47 (over EV; reads done; row ownership wv-disjoint).
  {
    float ev[3][3];
#pragma unroll
    for (int i = 0; i < 3; ++i) {
      const int r = wv + 8 * i;
#pragma unroll
      for (int c = 0; c < 3; ++c) {
        const int k = c * 64 + lane;
        ev[i][c] = (k < ND) ? bf2f(EV[r * EVS + k]) : 0.f;
      }
    }
#pragma unroll
    for (int i = 0; i < 3; ++i) {
      const int r = wv + 8 * i;
#pragma unroll
      for (int c = 0; c < 3; ++c) {
        const int k = c * 64 + lane;  // 0..191
        float u0v = 0.f, u1v = 0.f;
        if (k < ND) {
          const float e = ev[i][c];
          const float s = ps[i][c];
          const float t = pt[i][c];
          u0v = s + fmaxf(t + e, 0.f);
          u1v = t + fmaxf(s + e, 0.f);
        }
        U[r * US + k]        = f2bf(u0v);   // k in [172,192) zero = K-pad
        U[(24 + r) * US + k] = f2bf(u1v);   // overwrites EV row r
      }
    }
  }
  __syncthreads();

  // ============ phase 2b (MFMA): H[48][64] = relu(U[48][192] @ gcn_w1^T + b1) ============
  // M=48 = 3 m-tiles exactly. 12 (mtile,ntile) pairs over 8 waves:
  // wave w does p=w and p=w+8 (w<4). acc is loop-local scalar (no array).
  {
    const int np = (wv < 4) ? 2 : 1;
#pragma unroll 1
    for (int pp = 0; pp < np; ++pp) {
      const int p = wv + 8 * pp;       // 0..11
      const int mtile = p >> 2, ntb = p & 3;
      const int urow = mtile * 16 + mr;
      f32x4 acc = (f32x4){0.f, 0.f, 0.f, 0.f};
#pragma unroll 2
      for (int ks = 0; ks < 6; ++ks) {
        const int k0 = ks * 32 + q * 8;
        const bf16x8 a = *(const bf16x8*)&U[urow * US + k0];
        const bf16x8 b = *(const bf16x8*)&ws[G1OFF + ((ntb * 6 + ks) * 64 + lane) * 8];
        acc = __builtin_amdgcn_mfma_f32_16x16x32_bf16(a, b, acc, 0, 0, 0);
      }
      const int j = ntb * 16 + mr;
      const float b1 = gcn_b1[j];
#pragma unroll
      for (int reg = 0; reg < 4; ++reg) {
        const int m = mtile * 16 + q * 4 + reg;   // 0..47
        Hs[m * HS + j] = f2bf(fmaxf(acc[reg] + b1, 0.f));
      }
    }
  }
  __syncthreads();

  // ============ phase 2c (MFMA): FEATB/SRCF = H @ gcn_w2^T + b2 ============
  {
    const int np = (wv < 4) ? 2 : 1;
#pragma unroll 1
    for (int pp = 0; pp < np; ++pp) {
      const int p = wv + 8 * pp;       // 0..11
      const int mtile = p >> 2, ntb = p & 3;
      const int hrow = mtile * 16 + mr;
      f32x4 acc = (f32x4){0.f, 0.f, 0.f, 0.f};
#pragma unroll
      for (int ks = 0; ks < 2; ++ks) {
        const int k0 = ks * 32 + q * 8;
        const bf16x8 a = *(const bf16x8*)&Hs[hrow * HS + k0];
        const bf16x8 b = *(const bf16x8*)&ws[G2OFF + ((ntb * 2 + ks) * 64 + lane) * 8];
        acc = __builtin_amdgcn_mfma_f32_16x16x32_bf16(a, b, acc, 0, 0, 0);
      }
      const int j = ntb * 16 + mr;
      const float b2 = gcn_b2[j];
#pragma unroll
      for (int reg = 0; reg < 4; ++reg) {
        const int m = mtile * 16 + q * 4 + reg;   // 0..47
        const int d = (m < 24) ? 0 : 1;
        const int r = m - 24 * d;
        const float v = acc[reg] + b2;
        const int n = d * HID + j;
        FEATB[r * FBS + n] = f2bf(v);
        if (r % 3 == 2) SRCF[(r / 3) * 128 + n] = v;   // src feat, fp32
      }
    }
  }
  __syncthreads();

  // ============ phase 2d (MFMA): PQ = feat @ [att_w1 | att_w2]^T + bias ============
  // 16 n-tiles over 8 waves: nt = wv*2 + tt.  tt loops FULLY unrolled
  // (trip 2, compile-time acc indices — no local memory).
  {
    const int fr1 = (16 + mr < 24) ? (16 + mr) : 23;   // a1 garbage-row clamp
    f32x4 acc[2][2];
#pragma unroll
    for (int tt = 0; tt < 2; ++tt)
#pragma unroll
      for (int mt = 0; mt < 2; ++mt) acc[tt][mt] = (f32x4){0.f, 0.f, 0.f, 0.f};
#pragma unroll 2
    for (int ks = 0; ks < 4; ++ks) {
      const int k0 = ks * 32 + q * 8;
      const bf16x8 a0 = *(const bf16x8*)&FEATB[mr * FBS + k0];
      const bf16x8 a1 = *(const bf16x8*)&FEATB[fr1 * FBS + k0];
#pragma unroll
      for (int tt = 0; tt < 2; ++tt) {
        const int nt = wv * 2 + tt;
        const bf16x8 b = *(const bf16x8*)&ws[ATTOFF + ((nt * 4 + ks) * 64 + lane) * 8];
        acc[tt][0] = __builtin_amdgcn_mfma_f32_16x16x32_bf16(a0, b, acc[tt][0], 0, 0, 0);
        acc[tt][1] = __builtin_amdgcn_mfma_f32_16x16x32_bf16(a1, b, acc[tt][1], 0, 0, 0);
      }
    }
#pragma unroll
    for (int tt = 0; tt < 2; ++tt) {
      const int n = (wv * 2 + tt) * 16 + mr;   // 0..255
      const float bias = (n < D2) ? att_w1_b[n] : att_w2_b[n - D2];
#pragma unroll
      for (int mt = 0; mt < 2; ++mt)
#pragma unroll
        for (int reg = 0; reg < 4; ++reg) {
          const int m = mt * 16 + q * 4 + reg;
          if (m < 24) {
            const int l = m % 3;
            if (l == 2) { if (n < D2)  PQ[m * 128 + n]        = acc[tt][mt][reg] + bias; }
            else        { if (n >= D2) PQ[m * 128 + (n - D2)] = acc[tt][mt][reg] + bias; }
          }
        }
    }
  }
  __syncthreads();

  // ============ phase 3: softmax/out + MLP head — ONE window per wave ============
  {
    const int g = wv;
    float* Aw = SC + g * SCS;       // 128-float activation slot
    float* Bw = Aw + 128;           // 76-float hidden slot

    // softmax + out
    {
      const float p0  = PQ[(3 * g + 2) * 128 + lane];
      const float p1  = PQ[(3 * g + 2) * 128 + 64 + lane];
      const float q00 = PQ[(3 * g + 0) * 128 + lane];
      const float q01 = PQ[(3 * g + 0) * 128 + 64 + lane];
      const float q10 = PQ[(3 * g + 1) * 128 + lane];
      const float q11 = PQ[(3 * g + 1) * 128 + 64 + lane];
      float s0 = p0 * q00 + p1 * q01;
      float s1 = p0 * q10 + p1 * q11;
#pragma unroll
      for (int off = 32; off >= 1; off >>= 1) {
        s0 += __shfl_xor(s0, off, 64);
        s1 += __shfl_xor(s1, off, 64);
      }
      const float mx = fmaxf(s0, s1);
      const float e0 = __expf(s0 - mx), e1 = __expf(s1 - mx);
      const float inv = 1.f / (e0 + e1);
      const float a0 = e0 * inv, a1 = e1 * inv;
      Aw[lane]      = SRCF[g * 128 + lane]      + a0 * q00 + a1 * q10;
      Aw[64 + lane] = SRCF[g * 128 + 64 + lane] + a0 * q01 + a1 * q11;
    }

    const float4* M1P = wsf + M1OFF4;
    const float4* M2P = wsf + M2OFF4;
    const float4* W1P = wsf + W1OFF4;
    const float4* W2P = wsf + W2OFF4;

    // m1 = relu(att_m1 @ out + b): K=128 (dual accumulator chains)
    {
      float aa0 = 0.f, aa1 = 0.f;
#pragma unroll 4
      for (int kb = 0; kb < 32; kb += 2) {
        const float4 w0 = M1P[kb * 64 + lane];
        const float4 w1 = M1P[(kb + 1) * 64 + lane];
        const float4 x0 = *(const float4*)&Aw[kb * 4];
        const float4 x1 = *(const float4*)&Aw[kb * 4 + 4];
        aa0 = dot4(aa0, w0, x0); aa1 = dot4(aa1, w1, x1);
      }
      Bw[lane] = fmaxf(att_m1_b[lane] + aa0 + aa1, 0.f);
    }

    // h = att_m2 @ m1 + b: K=64
    float hv;
    {
      float aa0 = 0.f, aa1 = 0.f;
#pragma unroll 4
      for (int kb = 0; kb < 16; kb += 2) {
        const float4 w0 = M2P[kb * 64 + lane];
        const float4 w1 = M2P[(kb + 1) * 64 + lane];
        const float4 x0 = *(const float4*)&Bw[kb * 4];
        const float4 x1 = *(const float4*)&Bw[kb * 4 + 4];
        aa0 = dot4(aa0, w0, x0); aa1 = dot4(aa1, w1, x1);
      }
      hv = att_m2_b[lane] + aa0 + aa1;
    }

    // x = concat(h, one_hot(cat,12), 0-pad to 80) -> Aw (out is dead)
    Aw[lane] = hv;
    if (lane < 16) {
      const int ca = cat_feat[bw0 + g];
      Aw[64 + lane] = (lane < 12 && ca == lane) ? 1.f : 0.f;
    }

    // h1 = relu(mlp_w1 @ x + b1): 76 outs (n=lane, n2=64+lane for lane<12), K=80
    // Reads of Bw[76..79] later hit finite floats x ZERO k-pad weights -> 0.
    {
      float an = 0.f, an2 = 0.f;
      const int l2 = 64 + (lane & 15);
#pragma unroll 4
      for (int kb = 0; kb < 20; ++kb) {
        const float4 wn  = W1P[kb * 80 + lane];
        const float4 wn2 = W1P[kb * 80 + l2];
        const float4 x  = *(const float4*)&Aw[kb * 4];
        an  = dot4(an,  wn,  x);
        an2 = dot4(an2, wn2, x);
      }
      Bw[lane] = fmaxf(mlp_b1[lane] + an, 0.f);
      if (lane < 12) Bw[64 + lane] = fmaxf(mlp_b1[64 + lane] + an2, 0.f);
    }

    // h2 = relu(mlp_w2 @ h1 + b2); z = mlp_w3 @ h2 + b3; sigmoid
    {
      float ha = 0.f;
#pragma unroll 4
      for (int kb = 0; kb < 20; ++kb) {
        const float4 w = W2P[kb * 64 + lane];
        const float4 x = *(const float4*)&Bw[kb * 4];
        ha = dot4(ha, w, x);
      }
      const float h2 = fmaxf(mlp_b2[lane] + ha, 0.f);
      float zz = mlp_w3[lane] * h2;
#pragma unroll
      for (int off = 32; off >= 1; off >>= 1) zz += __shfl_xor(zz, off, 64);
      if (lane == 0) out[bw0 + g] = 1.f / (1.f + __expf(-(zz + mlp_b3[0])));
    }
  }
}

extern "C" void kernel_launch(void* const* d_in, const int* in_sizes, int n_in,
                              void* d_out, int out_size, void* d_ws, size_t ws_size,
                              hipStream_t stream) {
  short* ws = (short*)d_ws;
  float4* wsf = (float4*)((char*)d_ws + WSF_BYTE_OFF);
  prep_weights<<<(NFRAG * 64 + 255) / 256, 256, 0, stream>>>(
      (const float*)d_in[10],  // lin_event_w
      (const float*)d_in[12],  // gcn_w1
      (const float*)d_in[14],  // gcn_w2
      (const float*)d_in[16],  // att_w1_w
      (const float*)d_in[18],  // att_w2_w
      ws);
  prep_wf<<<(NF4 + 255) / 256, 256, 0, stream>>>(
      (const float*)d_in[20],  // att_m1_w
      (const float*)d_in[22],  // att_m2_w
      (const float*)d_in[24],  // mlp_w1
      (const float*)d_in[26],  // mlp_w2
      wsf);
  tempme_fused<<<NBLK, NT, 0, stream>>>(
      (const int*)d_in[0],    // node_idx
      (const int*)d_in[1],    // edge_idx
      (const int*)d_in[2],    // cat_feat
      (const float*)d_in[3],  // t_records
      (const float*)d_in[4],  // edge_identify
      // d_in[5] cut_time_l unused by reference
      (const float*)d_in[6],  // node_embed
      (const float*)d_in[7],  // edge_embed
      (const float*)d_in[8],  // basis_freq
      (const float*)d_in[9],  // phase
      (const float*)d_in[11],  // lin_event_b
      (const float*)d_in[13],  // gcn_b1
      (const float*)d_in[15],  // gcn_b2
      (const float*)d_in[17],  // att_w1_b
      (const float*)d_in[19],  // att_w2_b
      (const float*)d_in[21],  // att_m1_b
      (const float*)d_in[23],  // att_m2_b
      (const float*)d_in[25],  // mlp_b1
      (const float*)d_in[27],  // mlp_b2
      (const float*)d_in[28],  // mlp_w3
      (const float*)d_in[29],  // mlp_b3
      ws, wsf,
      (float*)d_out);
}